// Round 3
// baseline (2337.458 us; speedup 1.0000x reference)
//
#include <hip/hip_runtime.h>
#include <math.h>

#define T_LEN 256
#define B_SZ  64
#define IN_D  512
#define H_D   1024
#define G4    4096   // 4*H
#define SENT  0xFFFFFFFFu

typedef float  f32x4 __attribute__((ext_vector_type(4)));
typedef short  s16x8 __attribute__((ext_vector_type(8)));
typedef unsigned short u16;
typedef unsigned int   u32;

// ---------- helpers ----------
__device__ __forceinline__ void gl_lds16(const void* g, void* l) {
  __builtin_amdgcn_global_load_lds(
      (const __attribute__((address_space(1))) unsigned int*)g,
      (__attribute__((address_space(3))) unsigned int*)l, 16, 0, 0);
}

__device__ __forceinline__ u16 f2bf(float f) {
  union { float f; unsigned u; } v; v.f = f;
  unsigned x = v.u;
  unsigned r = (x + 0x7fffu + ((x >> 16) & 1u)) >> 16;  // RNE
  return (u16)r;
}
__device__ __forceinline__ float bf2f(u16 b) {
  union { unsigned u; float f; } v; v.u = ((unsigned)b) << 16;
  return v.f;
}
__device__ __forceinline__ float sigm(float x) {
  return 1.0f / (1.0f + __expf(-x));
}

// ---------- fp32 -> bf16 convert ----------
__global__ void cvt_f32_bf16(const float* __restrict__ src, u16* __restrict__ dst, int n) {
  int i = blockIdx.x * blockDim.x + threadIdx.x;
  int stride = gridDim.x * blockDim.x;
  for (; i < n; i += stride) dst[i] = f2bf(src[i]);
}

// ---------- generic bf16 GEMM: C[M,N] = A[M,K] * B[N,K]^T (+epilogue) ----------
template<int KD, int EPI>
__launch_bounds__(256)
__global__ void gemm_bt(const u16* __restrict__ A, const u16* __restrict__ Bm,
                        const float* __restrict__ bias, const float* __restrict__ img,
                        u16* __restrict__ Cb, float* __restrict__ Cf, int Ncols) {
  __shared__ u16 sA[128 * 64];
  __shared__ u16 sB[128 * 64];
  const int tid  = threadIdx.x;
  const int wave = tid >> 6, lane = tid & 63;
  const int wm = wave >> 1, wn = wave & 1;
  const int mBase = blockIdx.y * 128;
  const int nBase = blockIdx.x * 128;

  f32x4 acc[4][4] = {};

  for (int k0 = 0; k0 < KD; k0 += 64) {
#pragma unroll
    for (int it = 0; it < 4; ++it) {
      int s = it * 256 + tid;
      int row = s >> 3, c = s & 7;
      int gc = c ^ (row & 7);
      const u16* ga = A  + (size_t)(mBase + row) * KD + k0 + gc * 8;
      const u16* gb = Bm + (size_t)(nBase + row) * KD + k0 + gc * 8;
      gl_lds16(ga, &sA[(it * 256 + wave * 64) * 8]);
      gl_lds16(gb, &sB[(it * 256 + wave * 64) * 8]);
    }
    __syncthreads();

    const int q = lane >> 4, rl = lane & 15;
#pragma unroll
    for (int ks = 0; ks < 64; ks += 32) {
      s16x8 af[4], bfr[4];
      int gcb = (ks >> 3) + q;
#pragma unroll
      for (int i = 0; i < 4; ++i) {
        int rowA = wm * 64 + i * 16 + rl;
        af[i]  = *(const s16x8*)&sA[rowA * 64 + (gcb ^ (rowA & 7)) * 8];
        int rowB = wn * 64 + i * 16 + rl;
        bfr[i] = *(const s16x8*)&sB[rowB * 64 + (gcb ^ (rowB & 7)) * 8];
      }
#pragma unroll
      for (int i = 0; i < 4; ++i)
#pragma unroll
        for (int j = 0; j < 4; ++j)
          acc[i][j] = __builtin_amdgcn_mfma_f32_16x16x32_bf16(af[i], bfr[j], acc[i][j], 0, 0, 0);
    }
    __syncthreads();
  }

  // epilogue: C/D layout col=lane&15, row=(lane>>4)*4+r
#pragma unroll
  for (int i = 0; i < 4; ++i) {
    int rbase = mBase + wm * 64 + i * 16 + ((lane >> 4) << 2);
#pragma unroll
    for (int j = 0; j < 4; ++j) {
      int col = nBase + wn * 64 + j * 16 + (lane & 15);
      float bc = bias[col];
#pragma unroll
      for (int r = 0; r < 4; ++r) {
        int row = rbase + r;
        float v = acc[i][j][r] + bc;
        if (EPI == 0) {
          if (row < B_SZ) v += img[row * H_D + (col & (H_D - 1))];
          Cb[(size_t)row * Ncols + col] = f2bf(v);
        } else {
          Cf[(size_t)row * Ncols + col] = v;
        }
      }
    }
  }
}

// ---------- persistent LSTM recurrence ----------
// grid = 256 blocks = 4 batch-groups x 64 column-slices; block = 256 thr (4 waves).
// WG (grp,wg): batches [grp*16,+16), h-columns [wg*16,+16).
// Whh B-fragments live PERMANENTLY in VGPRs (32 x s16x8 = 128 VGPRs; 1 WG/CU so
// register budget is free) -> zero LDS traffic for B. h transport: data-IS-the-flag:
// hs pre-filled with 0xFFFFFFFF sentinel (bf16 pair 0xFFFF = NaN, impossible since
// h in (-1,1)); producers store relaxed agent-scope pair-dwords (sc1, LLC
// write-through, no waitcnt/flag needed); consumers speculative-load all 32 dwords
// and retry only sentinel stragglers. 2 syncthreads/step.
__launch_bounds__(256, 1)
__global__ void lstm_rec(const u16* __restrict__ WhhB, const u16* __restrict__ xproj,
                         const float* __restrict__ bhh, u32* __restrict__ hs32) {
  __shared__ u16  sH[16 * 1024];       // 32 KB full-K h tile (chunk-swizzled)
  __shared__ float sG[2][4][16][16];   // 8 KB gate exchange (t-parity)

  const int tid  = threadIdx.x;
  const int wave = tid >> 6, lane = tid & 63;
  const int grp = blockIdx.x >> 6;       // 0..3
  const int wg  = blockIdx.x & 63;       // 0..63
  const int bBase = grp * 16;
  const int colBase = wg * 16;
  const int q = lane >> 4, rl = lane & 15;

  // resident B-frags: bf[it] = Whh[wave*H + colBase + rl][it*32 + q*8 .. +7]
  s16x8 bf[32];
#pragma unroll
  for (int it = 0; it < 32; ++it)
    bf[it] = *(const s16x8*)(WhhB + (size_t)(wave * H_D + colBase + rl) * H_D + it * 32 + q * 8);

  float cst = 0.f;
  const int ub = tid >> 4, uc = tid & 15;     // (batch, col) for cell update
  const int gb = bBase + ub;
  const int gcol = colBase + uc;
  const float bh_i = bhh[0 * H_D + gcol], bh_f = bhh[1 * H_D + gcol];
  const float bh_g = bhh[2 * H_D + gcol], bh_o = bhh[3 * H_D + gcol];

  for (int t = 0; t < T_LEN; ++t) {
    // xproj loads issue first; latency hides under the h poll
    const u16* xp = xproj + ((size_t)t * B_SZ + gb) * G4;
    float gi_ = bf2f(xp[0 * H_D + gcol]) + bh_i;
    float gf_ = bf2f(xp[1 * H_D + gcol]) + bh_f;
    float gg_ = bf2f(xp[2 * H_D + gcol]) + bh_g;
    float go_ = bf2f(xp[3 * H_D + gcol]) + bh_o;

    if (t > 0) {
      const u32* hp = hs32 + (size_t)(t - 1) * B_SZ * 512 + (size_t)bBase * 512;
      // speculative bulk load: x4-chunk e = i*256+tid; row=e>>7, c16=e&127
      u32 v[32];
#pragma unroll
      for (int i = 0; i < 8; ++i) {
        int e = i * 256 + tid;
        int base = (e >> 7) * 512 + (e & 127) * 4;
#pragma unroll
        for (int d = 0; d < 4; ++d)
          v[i * 4 + d] = __hip_atomic_load(hp + base + d,
                                           __ATOMIC_RELAXED, __HIP_MEMORY_SCOPE_AGENT);
      }
      // straggler retry (sentinel = not yet written; each location written once)
#pragma unroll
      for (int i = 0; i < 8; ++i) {
        int e = i * 256 + tid;
        int base = (e >> 7) * 512 + (e & 127) * 4;
#pragma unroll
        for (int d = 0; d < 4; ++d)
          while (v[i * 4 + d] == SENT)
            v[i * 4 + d] = __hip_atomic_load(hp + base + d,
                                             __ATOMIC_RELAXED, __HIP_MEMORY_SCOPE_AGENT);
      }
      // scatter chunk (row,c16) -> sH[row][(c16 ^ (row&7))*8 ..]  (16B ds_write)
#pragma unroll
      for (int i = 0; i < 8; ++i) {
        int e = i * 256 + tid;
        int row = e >> 7, c16 = e & 127;
        u32* dst = (u32*)&sH[row * 1024 + (c16 ^ (row & 7)) * 8];
        dst[0] = v[i * 4 + 0]; dst[1] = v[i * 4 + 1];
        dst[2] = v[i * 4 + 2]; dst[3] = v[i * 4 + 3];
      }
      __syncthreads();

      // MFMA: 32 K-iters, 4 independent acc chains (1 wave/SIMD -> no TLP)
      f32x4 a0 = {}, a1 = {}, a2 = {}, a3 = {};
#pragma unroll
      for (int it = 0; it < 32; it += 4) {
        s16x8 f0 = *(const s16x8*)&sH[rl * 1024 + ((((it + 0) * 4 + q)) ^ (rl & 7)) * 8];
        s16x8 f1 = *(const s16x8*)&sH[rl * 1024 + ((((it + 1) * 4 + q)) ^ (rl & 7)) * 8];
        s16x8 f2 = *(const s16x8*)&sH[rl * 1024 + ((((it + 2) * 4 + q)) ^ (rl & 7)) * 8];
        s16x8 f3 = *(const s16x8*)&sH[rl * 1024 + ((((it + 3) * 4 + q)) ^ (rl & 7)) * 8];
        a0 = __builtin_amdgcn_mfma_f32_16x16x32_bf16(f0, bf[it + 0], a0, 0, 0, 0);
        a1 = __builtin_amdgcn_mfma_f32_16x16x32_bf16(f1, bf[it + 1], a1, 0, 0, 0);
        a2 = __builtin_amdgcn_mfma_f32_16x16x32_bf16(f2, bf[it + 2], a2, 0, 0, 0);
        a3 = __builtin_amdgcn_mfma_f32_16x16x32_bf16(f3, bf[it + 3], a3, 0, 0, 0);
      }
      f32x4 acc = (a0 + a1) + (a2 + a3);

      // gate exchange: wave g owns gate g tile; D layout row=q*4+r (batch), col=rl
#pragma unroll
      for (int r = 0; r < 4; ++r)
        sG[t & 1][wave][q * 4 + r][rl] = acc[r];
      __syncthreads();   // also orders all sH reads before next step's scatter
      gi_ += sG[t & 1][0][ub][uc]; gf_ += sG[t & 1][1][ub][uc];
      gg_ += sG[t & 1][2][ub][uc]; go_ += sG[t & 1][3][ub][uc];
    }

    // cell update: one (batch,col) per thread
    cst = sigm(gf_) * cst + sigm(gi_) * tanhf(gg_);
    float h = sigm(go_) * tanhf(cst);
    u32 bits = f2bf(h);
    u32 partner = (u32)__shfl_xor((int)bits, 1);
    if ((tid & 1) == 0) {
      // pair-dword (cols gcol,gcol+1) -> LLC; this store IS the ready signal
      __hip_atomic_store(&hs32[((size_t)t * B_SZ + gb) * 512 + (gcol >> 1)],
                         bits | (partner << 16),
                         __ATOMIC_RELAXED, __HIP_MEMORY_SCOPE_AGENT);
    }
  }
}

// ---------- in-place log_softmax over rows of 512 ----------
__launch_bounds__(256)
__global__ void logsoftmax_rows(float* __restrict__ out) {
  __shared__ float red[8];
  float* p = out + (size_t)blockIdx.x * IN_D;
  const int tid = threadIdx.x;
  float v0 = p[tid], v1 = p[tid + 256];
  float m = fmaxf(v0, v1);
#pragma unroll
  for (int off = 32; off > 0; off >>= 1) m = fmaxf(m, __shfl_down(m, off));
  if ((tid & 63) == 0) red[tid >> 6] = m;
  __syncthreads();
  m = fmaxf(fmaxf(red[0], red[1]), fmaxf(red[2], red[3]));
  float e = __expf(v0 - m) + __expf(v1 - m);
#pragma unroll
  for (int off = 32; off > 0; off >>= 1) e += __shfl_down(e, off);
  if ((tid & 63) == 0) red[4 + (tid >> 6)] = e;
  __syncthreads();
  float ls = m + logf(red[4] + red[5] + red[6] + red[7]);
  p[tid] = v0 - ls;
  p[tid + 256] = v1 - ls;
}

// ---------- launch ----------
extern "C" void kernel_launch(void* const* d_in, const int* in_sizes, int n_in,
                              void* d_out, int out_size, void* d_ws, size_t ws_size,
                              hipStream_t stream) {
  const float* inp  = (const float*)d_in[0];
  const float* img  = (const float*)d_in[1];
  const float* Wxh  = (const float*)d_in[2];
  const float* bxh  = (const float*)d_in[3];
  const float* Whh  = (const float*)d_in[4];
  const float* bhh  = (const float*)d_in[5];
  const float* Wout = (const float*)d_in[6];
  const float* bout = (const float*)d_in[7];
  float* out = (float*)d_out;

  char* ws = (char*)d_ws;
  u16* inpB   = (u16*)(ws);                    // 16 MB  (256*64*512)
  u16* WxhB   = (u16*)(ws + 16777216);         // 4 MB   (4096*512)
  u16* WhhB   = (u16*)(ws + 20971520);         // 8 MB   (4096*1024)
  u16* WoutB  = (u16*)(ws + 29360128);         // 1 MB   (512*1024)
  u16* xprojB = (u16*)(ws + 30408704);         // 128 MB (16384*4096)
  u16* hsB    = (u16*)(ws + 164626432);        // 32 MB  (256*64*1024)

  cvt_f32_bf16<<<2048, 256, 0, stream>>>(inp,  inpB,  T_LEN * B_SZ * IN_D);
  cvt_f32_bf16<<<2048, 256, 0, stream>>>(Wxh,  WxhB,  G4 * IN_D);
  cvt_f32_bf16<<<2048, 256, 0, stream>>>(Whh,  WhhB,  G4 * H_D);
  cvt_f32_bf16<<<2048, 256, 0, stream>>>(Wout, WoutB, IN_D * H_D);
  // sentinel-fill hs: 0xFFFFFFFF dwords (bf16 NaN pair — unreachable as data)
  hipMemsetAsync(hsB, 0xFF, (size_t)T_LEN * B_SZ * H_D * sizeof(u16), stream);

  // xproj = inp@Wxh^T + bxh (+ img4 at t=0), bf16 out
  gemm_bt<IN_D, 0><<<dim3(G4 / 128, 16384 / 128), 256, 0, stream>>>(
      inpB, WxhB, bxh, img, xprojB, nullptr, G4);

  lstm_rec<<<256, 256, 0, stream>>>(WhhB, xprojB, bhh, (u32*)hsB);

  // logits = hs@Wout^T + bout, f32 into d_out
  gemm_bt<H_D, 1><<<dim3(IN_D / 128, 16384 / 128), 256, 0, stream>>>(
      hsB, WoutB, bout, nullptr, nullptr, out, IN_D);

  logsoftmax_rows<<<16384, 256, 0, stream>>>(out);
}

// Round 6
// 1867.969 us; speedup vs baseline: 1.2513x; 1.2513x over previous
//
#include <hip/hip_runtime.h>
#include <math.h>

#define T_LEN 256
#define B_SZ  64
#define IN_D  512
#define H_D   1024
#define G4    4096   // 4*H

typedef float  f32x4 __attribute__((ext_vector_type(4)));
typedef short  s16x8 __attribute__((ext_vector_type(8)));
typedef unsigned short u16;
typedef unsigned int   u32;

// ---------- helpers ----------
__device__ __forceinline__ void gl_lds16(const void* g, void* l) {
  __builtin_amdgcn_global_load_lds(
      (const __attribute__((address_space(1))) unsigned int*)g,
      (__attribute__((address_space(3))) unsigned int*)l, 16, 0, 0);
}

__device__ __forceinline__ u16 f2bf(float f) {
  union { float f; unsigned u; } v; v.f = f;
  unsigned x = v.u;
  unsigned r = (x + 0x7fffu + ((x >> 16) & 1u)) >> 16;  // RNE
  return (u16)r;
}
__device__ __forceinline__ float bf2f(u16 b) {
  union { unsigned u; float f; } v; v.u = ((unsigned)b) << 16;
  return v.f;
}
__device__ __forceinline__ float sigm(float x) {
  return 1.0f / (1.0f + __expf(-x));
}

// ---------- fp32 -> bf16 convert ----------
__global__ void cvt_f32_bf16(const float* __restrict__ src, u16* __restrict__ dst, int n) {
  int i = blockIdx.x * blockDim.x + threadIdx.x;
  int stride = gridDim.x * blockDim.x;
  for (; i < n; i += stride) dst[i] = f2bf(src[i]);
}

// ---------- generic bf16 GEMM: C[M,N] = A[M,K] * B[N,K]^T (+epilogue) ----------
template<int KD, int EPI>
__launch_bounds__(256)
__global__ void gemm_bt(const u16* __restrict__ A, const u16* __restrict__ Bm,
                        const float* __restrict__ bias, const float* __restrict__ img,
                        u16* __restrict__ Cb, float* __restrict__ Cf, int Ncols) {
  __shared__ u16 sA[128 * 64];
  __shared__ u16 sB[128 * 64];
  const int tid  = threadIdx.x;
  const int wave = tid >> 6, lane = tid & 63;
  const int wm = wave >> 1, wn = wave & 1;
  const int mBase = blockIdx.y * 128;
  const int nBase = blockIdx.x * 128;

  f32x4 acc[4][4] = {};

  for (int k0 = 0; k0 < KD; k0 += 64) {
#pragma unroll
    for (int it = 0; it < 4; ++it) {
      int s = it * 256 + tid;
      int row = s >> 3, c = s & 7;
      int gc = c ^ (row & 7);
      const u16* ga = A  + (size_t)(mBase + row) * KD + k0 + gc * 8;
      const u16* gb = Bm + (size_t)(nBase + row) * KD + k0 + gc * 8;
      gl_lds16(ga, &sA[(it * 256 + wave * 64) * 8]);
      gl_lds16(gb, &sB[(it * 256 + wave * 64) * 8]);
    }
    __syncthreads();

    const int q = lane >> 4, rl = lane & 15;
#pragma unroll
    for (int ks = 0; ks < 64; ks += 32) {
      s16x8 af[4], bfr[4];
      int gcb = (ks >> 3) + q;
#pragma unroll
      for (int i = 0; i < 4; ++i) {
        int rowA = wm * 64 + i * 16 + rl;
        af[i]  = *(const s16x8*)&sA[rowA * 64 + (gcb ^ (rowA & 7)) * 8];
        int rowB = wn * 64 + i * 16 + rl;
        bfr[i] = *(const s16x8*)&sB[rowB * 64 + (gcb ^ (rowB & 7)) * 8];
      }
#pragma unroll
      for (int i = 0; i < 4; ++i)
#pragma unroll
        for (int j = 0; j < 4; ++j)
          acc[i][j] = __builtin_amdgcn_mfma_f32_16x16x32_bf16(af[i], bfr[j], acc[i][j], 0, 0, 0);
    }
    __syncthreads();
  }

  // epilogue: C/D layout col=lane&15, row=(lane>>4)*4+r
#pragma unroll
  for (int i = 0; i < 4; ++i) {
    int rbase = mBase + wm * 64 + i * 16 + ((lane >> 4) << 2);
#pragma unroll
    for (int j = 0; j < 4; ++j) {
      int col = nBase + wn * 64 + j * 16 + (lane & 15);
      float bc = bias[col];
#pragma unroll
      for (int r = 0; r < 4; ++r) {
        int row = rbase + r;
        float v = acc[i][j][r] + bc;
        if (EPI == 0) {
          if (row < B_SZ) v += img[row * H_D + (col & (H_D - 1))];
          Cb[(size_t)row * Ncols + col] = f2bf(v);
        } else {
          Cf[(size_t)row * Ncols + col] = v;
        }
      }
    }
  }
}

// ---------- persistent LSTM recurrence ----------
// grid = 256 blocks = 4 batch-groups x 64 column-slices; block = 256 thr (4 waves).
// WG (grp,wg): batches [grp*16,+16), h-columns [wg*16,+16).
// Partition: wave w owns columns colBase+w*4..+4 for ALL 4 gates (B-tile row
// n = g*4+j <-> Whh row g*H + colBase + w*4 + j); the 4 gates of a cell live in
// one wave -> gate exchange = 4x4 lane transpose via __shfl (no LDS).
// Whh B-frags resident in VGPRs (32 x s16x8 = 128 VGPR), pinned with opaque asm.
// LDS = double-buffered sH (2 x 32 KB).
// Transport = r2-PROVEN explicit flag handshake (r4's sentinel data-is-the-flag
// was replay-flaky + slow): producer h pair-stores (relaxed agent, sc1) ->
// s_waitcnt(0) -> barrier -> one flag store per WG; consumer: 64 lanes spin on
// the group's 64 flags -> barrier -> single bulk h load (no retry) -> scatter.
__launch_bounds__(256, 1)
__global__ void lstm_rec(const u16* __restrict__ WhhB, const u16* __restrict__ xproj,
                         const float* __restrict__ bhh, u32* __restrict__ hs32,
                         int* __restrict__ flags) {
  __shared__ u16 sH[2][16 * 1024];    // 64 KB double-buffered h tile (swizzled)

  const int tid  = threadIdx.x;
  const int wave = tid >> 6, lane = tid & 63;
  const int grp = blockIdx.x >> 6;       // 0..3
  const int wg  = blockIdx.x & 63;       // 0..63
  const int bBase = grp * 16;
  const int colBase = wg * 16;
  const int q  = lane >> 4;              // 0..3 (k-quad / batch-quad)
  const int rl = lane & 15;              // B/D tile row-col index n
  const int g  = rl >> 2, j = rl & 3;    // gate, within-wave col
  const int myCol = colBase + wave * 4 + j;   // this lane's h column
  const int myB   = bBase + q * 4 + g;        // this lane's batch

  // resident B-frags: bf[it] = Whh[g*H + myCol][it*32 + q*8 .. +7]
  s16x8 bf[32];
  const u16* wp = WhhB + (size_t)(g * H_D + myCol) * H_D + q * 8;
#pragma unroll
  for (int it = 0; it < 32; ++it)
    bf[it] = *(const s16x8*)(wp + it * 32);
#pragma unroll
  for (int it = 0; it < 32; ++it)
    asm volatile("" : "+v"(bf[it]));    // opaque def: loads cannot be re-sunk

  float cst = 0.f;
  const float bh_i = bhh[0 * H_D + myCol], bh_f = bhh[1 * H_D + myCol];
  const float bh_g = bhh[2 * H_D + myCol], bh_o = bhh[3 * H_D + myCol];

  for (int t = 0; t < T_LEN; ++t) {
    const u16* xp = xproj + ((size_t)t * B_SZ + myB) * G4 + myCol;
    // xproj raw loads issue early; HBM latency hides under the flag spin
    u16 x0 = xp[0], x1 = xp[H_D], x2 = xp[2 * H_D], x3 = xp[3 * H_D];
    float gi_, gf_, gg_, go_;

    if (t > 0) {
      // 1) wait for all 64 producers of this group's h[t-1]
      if (tid < 64) {
        const int* fp = flags + (t - 1) * 256 + grp * 64 + tid;
        while (__hip_atomic_load(fp, __ATOMIC_RELAXED, __HIP_MEMORY_SCOPE_AGENT) == 0)
          __builtin_amdgcn_s_sleep(1);
      }
      __syncthreads();

      // 2) single bulk load of h[t-1] (flags guarantee data is at LLC)
      u32 v[32];
      const u32* hp = hs32 + ((size_t)(t - 1) * B_SZ + bBase) * 512;
#pragma unroll
      for (int i = 0; i < 8; ++i) {
        int e = i * 256 + tid;                  // 16B chunk: row=e>>7, c16=e&127
        int base = (e >> 7) * 512 + (e & 127) * 4;
#pragma unroll
        for (int d = 0; d < 4; ++d)
          v[i * 4 + d] = __hip_atomic_load(hp + base + d,
                                           __ATOMIC_RELAXED, __HIP_MEMORY_SCOPE_AGENT);
      }

      // 3) scatter into swizzled sH[t&1]: chunk (row,c16) -> (c16 ^ (row&7))
      u16* shb = sH[t & 1];
#pragma unroll
      for (int i = 0; i < 8; ++i) {
        int e = i * 256 + tid;
        int row = e >> 7, c16 = e & 127;
        u32* dst = (u32*)&shb[row * 1024 + (c16 ^ (row & 7)) * 8];
        dst[0] = v[i * 4 + 0]; dst[1] = v[i * 4 + 1];
        dst[2] = v[i * 4 + 2]; dst[3] = v[i * 4 + 3];
      }
      __syncthreads();

      // 4) MFMA: 32 K-iters, 4 independent chains; A from sH, B from VGPRs
      f32x4 a0 = {}, a1 = {}, a2 = {}, a3 = {};
      const u16* hrow = &shb[rl * 1024];
#pragma unroll
      for (int it = 0; it < 32; it += 4) {
        s16x8 f0 = *(const s16x8*)&hrow[(((it + 0) * 4 + q) ^ (rl & 7)) * 8];
        s16x8 f1 = *(const s16x8*)&hrow[(((it + 1) * 4 + q) ^ (rl & 7)) * 8];
        s16x8 f2 = *(const s16x8*)&hrow[(((it + 2) * 4 + q) ^ (rl & 7)) * 8];
        s16x8 f3 = *(const s16x8*)&hrow[(((it + 3) * 4 + q) ^ (rl & 7)) * 8];
        a0 = __builtin_amdgcn_mfma_f32_16x16x32_bf16(f0, bf[it + 0], a0, 0, 0, 0);
        a1 = __builtin_amdgcn_mfma_f32_16x16x32_bf16(f1, bf[it + 1], a1, 0, 0, 0);
        a2 = __builtin_amdgcn_mfma_f32_16x16x32_bf16(f2, bf[it + 2], a2, 0, 0, 0);
        a3 = __builtin_amdgcn_mfma_f32_16x16x32_bf16(f3, bf[it + 3], a3, 0, 0, 0);
      }
      f32x4 facc = (a0 + a1) + (a2 + a3);
      // facc[r] = D[batch q*4+r][n=rl] = gate g, col myCol, batch bBase+q*4+r

      // 5) 4x4 lane transpose: lane (batch q*4+g, col j) gathers gate gp from
      //    lane q*16 + gp*4 + j, component g.
      float gv[4];
#pragma unroll
      for (int gp = 0; gp < 4; ++gp) {
        int src = (lane & 48) + gp * 4 + j;
        float r0 = __shfl(facc[0], src);
        float r1 = __shfl(facc[1], src);
        float r2 = __shfl(facc[2], src);
        float r3 = __shfl(facc[3], src);
        gv[gp] = (g & 2) ? ((g & 1) ? r3 : r2) : ((g & 1) ? r1 : r0);
      }
      gi_ = gv[0] + bf2f(x0) + bh_i;
      gf_ = gv[1] + bf2f(x1) + bh_f;
      gg_ = gv[2] + bf2f(x2) + bh_g;
      go_ = gv[3] + bf2f(x3) + bh_o;
    } else {
      gi_ = bf2f(x0) + bh_i;
      gf_ = bf2f(x1) + bh_f;
      gg_ = bf2f(x2) + bh_g;
      go_ = bf2f(x3) + bh_o;
    }

    // cell update: this lane owns cell (myB, myCol)
    cst = sigm(gf_) * cst + sigm(gi_) * tanhf(gg_);
    float h = sigm(go_) * tanhf(cst);
    u32 bits = f2bf(h);
    u32 part = (u32)__shfl_xor((int)bits, 1);   // partner col myCol^1 (same g,q)
    if ((j & 1) == 0) {
      // pair-dword (cols myCol,myCol+1) -> LLC (relaxed agent, write-through)
      __hip_atomic_store(&hs32[((size_t)t * B_SZ + myB) * 512 + (myCol >> 1)],
                         bits | (part << 16),
                         __ATOMIC_RELAXED, __HIP_MEMORY_SCOPE_AGENT);
    }
    __builtin_amdgcn_s_waitcnt(0);   // per-wave: h stores acked at LLC
    __syncthreads();                 // all 4 waves drained
    if (tid == 0)
      __hip_atomic_store(&flags[t * 256 + grp * 64 + wg], 1,
                         __ATOMIC_RELAXED, __HIP_MEMORY_SCOPE_AGENT);
  }
}

// ---------- in-place log_softmax over rows of 512 ----------
__launch_bounds__(256)
__global__ void logsoftmax_rows(float* __restrict__ out) {
  __shared__ float red[8];
  float* p = out + (size_t)blockIdx.x * IN_D;
  const int tid = threadIdx.x;
  float v0 = p[tid], v1 = p[tid + 256];
  float m = fmaxf(v0, v1);
#pragma unroll
  for (int off = 32; off > 0; off >>= 1) m = fmaxf(m, __shfl_down(m, off));
  if ((tid & 63) == 0) red[tid >> 6] = m;
  __syncthreads();
  m = fmaxf(fmaxf(red[0], red[1]), fmaxf(red[2], red[3]));
  float e = __expf(v0 - m) + __expf(v1 - m);
#pragma unroll
  for (int off = 32; off > 0; off >>= 1) e += __shfl_down(e, off);
  if ((tid & 63) == 0) red[4 + (tid >> 6)] = e;
  __syncthreads();
  float ls = m + logf(red[4] + red[5] + red[6] + red[7]);
  p[tid] = v0 - ls;
  p[tid + 256] = v1 - ls;
}

// ---------- launch ----------
extern "C" void kernel_launch(void* const* d_in, const int* in_sizes, int n_in,
                              void* d_out, int out_size, void* d_ws, size_t ws_size,
                              hipStream_t stream) {
  const float* inp  = (const float*)d_in[0];
  const float* img  = (const float*)d_in[1];
  const float* Wxh  = (const float*)d_in[2];
  const float* bxh  = (const float*)d_in[3];
  const float* Whh  = (const float*)d_in[4];
  const float* bhh  = (const float*)d_in[5];
  const float* Wout = (const float*)d_in[6];
  const float* bout = (const float*)d_in[7];
  float* out = (float*)d_out;

  char* ws = (char*)d_ws;
  u16* inpB   = (u16*)(ws);                    // 16 MB  (256*64*512)
  u16* WxhB   = (u16*)(ws + 16777216);         // 4 MB   (4096*512)
  u16* WhhB   = (u16*)(ws + 20971520);         // 8 MB   (4096*1024)
  u16* WoutB  = (u16*)(ws + 29360128);         // 1 MB   (512*1024)
  u16* xprojB = (u16*)(ws + 30408704);         // 128 MB (16384*4096)
  u16* hsB    = (u16*)(ws + 164626432);        // 32 MB  (256*64*1024)
  int* flags  = (int*)(ws + 198180864);        // 256 KB (256*256)

  cvt_f32_bf16<<<2048, 256, 0, stream>>>(inp,  inpB,  T_LEN * B_SZ * IN_D);
  cvt_f32_bf16<<<2048, 256, 0, stream>>>(Wxh,  WxhB,  G4 * IN_D);
  cvt_f32_bf16<<<2048, 256, 0, stream>>>(Whh,  WhhB,  G4 * H_D);
  cvt_f32_bf16<<<2048, 256, 0, stream>>>(Wout, WoutB, IN_D * H_D);
  (void)hipMemsetAsync(flags, 0, T_LEN * 256 * sizeof(int), stream);

  // xproj = inp@Wxh^T + bxh (+ img4 at t=0), bf16 out
  gemm_bt<IN_D, 0><<<dim3(G4 / 128, 16384 / 128), 256, 0, stream>>>(
      inpB, WxhB, bxh, img, xprojB, nullptr, G4);

  lstm_rec<<<256, 256, 0, stream>>>(WhhB, xprojB, bhh, (u32*)hsB, flags);

  // logits = hs@Wout^T + bout, f32 into d_out
  gemm_bt<H_D, 1><<<dim3(IN_D / 128, 16384 / 128), 256, 0, stream>>>(
      hsB, WoutB, bout, nullptr, nullptr, out, IN_D);

  logsoftmax_rows<<<16384, 256, 0, stream>>>(out);
}